// Round 13
// baseline (6410.141 us; speedup 1.0000x reference)
//
#include <hip/hip_runtime.h>
#include <hip/hip_bf16.h>
#include <stdint.h>

#define B_  4
#define N0  8192
#define S1  4096
#define S2  2048
#define KNB 32

static constexpr float EPS_IN_ = 1e-5f;

// ---------------- FPS body (golden index path + wave-granular lazy skip) ----------------
// d2 must match numpy exactly: (dx*dx + dy*dy) + dz*dz, all round-nearest,
// NO FMA contraction -> `#pragma clang fp contract(off)`.
// Points Morton-sorted (4x4x4 cells) so each WAVE owns a spatially compact
// slice with bounding sphere (g, rr). Per iteration, uniform wave branch:
// if |c-g|^2 > (rr+sqrt(UB))^2*1.0001 then every exact-RN d2 >= wave's max
// dist => fmin is a provable no-op for ALL its points -> wave skips phase A
// and re-posts its cached exact key. Keys use ORIGINAL indices (sort-order
// invariant); tie-break = min orig idx among bit-equal maxima (numpy
// first-argmax). DPP wave reduce, u64 key/wave, ONE barrier, phase B and
// coord broadcast (lpk by orig idx) byte-identical to the proven round-9 code.
template<int N, int NP, bool CHFIRST>
__device__ __forceinline__ void fps_body(
    const float* __restrict__ base, float* __restrict__ fidx_out,
    float* __restrict__ newxyz, float* __restrict__ out_t,
    float4* __restrict__ lpk, unsigned short* __restrict__ soid,
    unsigned short* __restrict__ sidx, unsigned int* __restrict__ cellc,
    unsigned long long* __restrict__ kq)
{
  constexpr int NT = 512;
  constexpr int PPT = N / NT;
  constexpr int WPW = 64 * PPT;           // points per wave (slice)
  const int tid = threadIdx.x;
  const int lane = tid & 63;
  const int wid = tid >> 6;

  // ---- load points (coalesced), write lpk by ORIG idx, Morton cell ids ----
  int mc[PPT];
  if (tid < 64) cellc[tid] = 0;
#pragma unroll
  for (int j = 0; j < PPT; ++j) {
    int p = tid + j * NT;
    float x, y, z;
    if (CHFIRST) { x = base[p];   y = base[N + p];   z = base[2*N + p]; }
    else         { x = base[3*p]; y = base[3*p + 1]; z = base[3*p + 2]; }
    lpk[p] = make_float4(x, y, z, 0.f);
    int cx = (int)floorf((x + 3.f) * 0.6666667f); cx = cx < 0 ? 0 : (cx > 3 ? 3 : cx);
    int cy = (int)floorf((y + 3.f) * 0.6666667f); cy = cy < 0 ? 0 : (cy > 3 ? 3 : cy);
    int cz = (int)floorf((z + 3.f) * 0.6666667f); cz = cz < 0 ? 0 : (cz > 3 ? 3 : cz);
    mc[j] = (cx & 1) | ((cy & 1) << 1) | ((cz & 1) << 2) |
            ((cx & 2) << 2) | ((cy & 2) << 3) | ((cz & 2) << 4);
  }
  __syncthreads();
#pragma unroll
  for (int j = 0; j < PPT; ++j) atomicAdd(&cellc[mc[j]], 1u);
  __syncthreads();
  if (tid == 0) {
    unsigned run = 0;
    for (int c2 = 0; c2 < 64; ++c2) { unsigned v = cellc[c2]; cellc[c2] = run; run += v; }
    sidx[0] = 0;
  }
  __syncthreads();
#pragma unroll
  for (int j = 0; j < PPT; ++j) {
    unsigned pos = atomicAdd(&cellc[mc[j]], 1u);
    soid[pos] = (unsigned short)(tid + j * NT);
  }
  __syncthreads();
  // ---- wave-slice register load (orig-index indirection) + bounding sphere ----
  float px[PPT], py[PPT], pz[PPT], dist[PPT];
  int oid_[PPT];
  float mnx = 1e30f, mny = 1e30f, mnz = 1e30f, mxx = -1e30f, mxy = -1e30f, mxz = -1e30f;
#pragma unroll
  for (int j = 0; j < PPT; ++j) {
    int pos = wid * WPW + lane + (j << 6);
    int o = soid[pos];
    float4 c = lpk[o];
    px[j] = c.x; py[j] = c.y; pz[j] = c.z; oid_[j] = o;
    dist[j] = 1e10f;
    mnx = fminf(mnx, c.x); mny = fminf(mny, c.y); mnz = fminf(mnz, c.z);
    mxx = fmaxf(mxx, c.x); mxy = fmaxf(mxy, c.y); mxz = fmaxf(mxz, c.z);
  }
#pragma unroll
  for (int off = 32; off; off >>= 1) {
    mnx = fminf(mnx, __shfl_xor(mnx, off)); mny = fminf(mny, __shfl_xor(mny, off));
    mnz = fminf(mnz, __shfl_xor(mnz, off)); mxx = fmaxf(mxx, __shfl_xor(mxx, off));
    mxy = fmaxf(mxy, __shfl_xor(mxy, off)); mxz = fmaxf(mxz, __shfl_xor(mxz, off));
  }
  const float gx = (mnx + mxx) * 0.5f, gy = (mny + mxy) * 0.5f, gz = (mnz + mxz) * 0.5f;
  float r2 = 0.f;
#pragma unroll
  for (int j = 0; j < PPT; ++j) {
    float dx = px[j] - gx, dy = py[j] - gy, dz = pz[j] - gz;
    r2 = fmaxf(r2, dx * dx + dy * dy + dz * dz);
  }
#pragma unroll
  for (int off = 32; off; off >>= 1) r2 = fmaxf(r2, __shfl_xor(r2, off));
  const float rr = sqrtf(r2) * 1.00001f + 1e-6f;   // upper bound of slice radius

  float bx = lpk[0].x, by = lpk[0].y, bz = lpk[0].z;
  unsigned long long ckey = 0ull;    // cached wave key (exact after first refresh)
  float sUB = 1e5f;                  // upper bound of sqrt(wave max dist)

  for (int i = 1; i < NP; ++i) {
    const int par = i & 1;
    // ---- wave-uniform skip test (conservative; skip only when provable no-op) ----
    float dgx = bx - gx, dgy = by - gy, dgz = bz - gz;
    float D = dgx * dgx + dgy * dgy + dgz * dgz;
    float thr = rr + sUB;
    if (D <= thr * thr * 1.0001f) {
      // ---- refresh: phase A value-only max (exact numpy arithmetic) ----
      float bv = -1.f;
#pragma unroll
      for (int j = 0; j < PPT; ++j) {
#pragma clang fp contract(off)
        float dx = px[j] - bx;
        float dy = py[j] - by;
        float dz = pz[j] - bz;
        float d2 = (dx * dx + dy * dy) + dz * dz;   // strict numpy order, no FMA
        float nd = fminf(dist[j], d2);
        dist[j] = nd;
        bv = fmaxf(bv, nd);
      }
      int wmax_bits;
      {
        int x = __float_as_int(bv), t;
        t = __builtin_amdgcn_update_dpp(0, x, 0x111, 0xf, 0xf, false);
        x = __float_as_int(fmaxf(__int_as_float(x), __int_as_float(t)));
        t = __builtin_amdgcn_update_dpp(0, x, 0x112, 0xf, 0xf, false);
        x = __float_as_int(fmaxf(__int_as_float(x), __int_as_float(t)));
        t = __builtin_amdgcn_update_dpp(0, x, 0x114, 0xf, 0xf, false);
        x = __float_as_int(fmaxf(__int_as_float(x), __int_as_float(t)));
        t = __builtin_amdgcn_update_dpp(0, x, 0x118, 0xf, 0xf, false);
        x = __float_as_int(fmaxf(__int_as_float(x), __int_as_float(t)));
        t = __builtin_amdgcn_update_dpp(0, x, 0x142, 0xa, 0xf, false);
        x = __float_as_int(fmaxf(__int_as_float(x), __int_as_float(t)));
        t = __builtin_amdgcn_update_dpp(0, x, 0x143, 0xc, 0xf, false);
        x = __float_as_int(fmaxf(__int_as_float(x), __int_as_float(t)));
        wmax_bits = __builtin_amdgcn_readlane(x, 63);
      }
      // in-thread min ORIGINAL idx among bit-equal maxima
      // (a lane with bv < wmax cannot have dist[j]==wmax: dist[j] <= bv < wmax)
      int m0 = 0x7fffffff;
#pragma unroll
      for (int j = 0; j < PPT; ++j)
        if (__float_as_int(dist[j]) == wmax_bits) m0 = min(m0, oid_[j]);
      {
        int t;
        t = __builtin_amdgcn_update_dpp(0x7fffffff, m0, 0x111, 0xf, 0xf, false);
        m0 = min(m0, t);
        t = __builtin_amdgcn_update_dpp(0x7fffffff, m0, 0x112, 0xf, 0xf, false);
        m0 = min(m0, t);
        t = __builtin_amdgcn_update_dpp(0x7fffffff, m0, 0x114, 0xf, 0xf, false);
        m0 = min(m0, t);
        t = __builtin_amdgcn_update_dpp(0x7fffffff, m0, 0x118, 0xf, 0xf, false);
        m0 = min(m0, t);
        t = __builtin_amdgcn_update_dpp(0x7fffffff, m0, 0x142, 0xa, 0xf, false);
        m0 = min(m0, t);
        t = __builtin_amdgcn_update_dpp(0x7fffffff, m0, 0x143, 0xc, 0xf, false);
        m0 = min(m0, t);
        const int widx = __builtin_amdgcn_readlane(m0, 63);
        ckey = ((unsigned long long)(unsigned)wmax_bits << 32) |
               (uint32_t)(~(uint32_t)widx);
      }
      sUB = sqrtf(__int_as_float(wmax_bits)) * 1.000001f;
    }
    if (lane == 0) kq[par * 8 + wid] = ckey;
    __syncthreads();                   // the ONE barrier
    // ---- phase B: 8-key u64 max + broadcast coord read (round-9 exact) ----
    unsigned long long g = kq[par * 8 + 0];
#pragma unroll
    for (int w = 1; w < 8; ++w) {
      unsigned long long t2 = kq[par * 8 + w];
      g = (t2 > g) ? t2 : g;
    }
    const int wi = (int)(~(uint32_t)g);
    float4 c = lpk[wi];
    bx = c.x; by = c.y; bz = c.z;
    if (tid == 0) sidx[i] = (unsigned short)wi;
  }
  __syncthreads();
  for (int s = tid; s < NP; s += NT) {
    int id = sidx[s];
    float4 c = lpk[id];
    fidx_out[s] = (float)id;
    newxyz[s * 3 + 0] = c.x;
    newxyz[s * 3 + 1] = c.y;
    newxyz[s * 3 + 2] = c.z;
    out_t[s] = c.x; out_t[NP + s] = c.y; out_t[2 * NP + s] = c.z;
  }
}

template<int N, int NP, bool CHFIRST>
__global__ __launch_bounds__(512)
void fps_kernel(const float* __restrict__ pts, float* __restrict__ fidx_out,
                float* __restrict__ newxyz, float* __restrict__ out_t)
{
  __shared__ float4 lpk[N];
  __shared__ unsigned short soid[N];
  __shared__ unsigned short sidx[NP];
  __shared__ unsigned int cellc[64];
  __shared__ unsigned long long kq[16];
  const int b = blockIdx.x;
  fps_body<N, NP, CHFIRST>(pts + (size_t)b * 3 * N, fidx_out + (size_t)b * NP,
                           newxyz + (size_t)b * NP * 3, out_t + (size_t)b * 3 * NP,
                           lpk, soid, sidx, cellc, kq);
}

// ---------------- exact kNN body (NT-generic, parallel scans) ----------------
template<int NT, int N, bool CHFIRST>
__device__ __forceinline__ void knn_body(const float* __restrict__ base,
                                         const float* __restrict__ qp,
                                         int* __restrict__ outq, char* __restrict__ sm,
                                         int tid)
{
  constexpr int PPT = N / NT;
  constexpr int NW = NT / 64;
  constexpr int HB = 4096;
  constexpr int BPT = HB / NT;
  const int lane = tid & 63, wid = tid >> 6;

  uint32_t* key  = (uint32_t*)sm;
  uint32_t* hist = key + N;
  uint32_t* wtot = hist + HB;
  uint32_t* wk   = wtot + NW;
  int*      wi2  = (int*)(wk + NW);
  int*      sc   = wi2 + NW;

  const float qx = qp[0], qy = qp[1], qz = qp[2];
  for (int h = tid; h < HB; h += NT) hist[h] = 0;
  __syncthreads();
  for (int c = 0; c < PPT; ++c) {
    int p = c * NT + tid;
    float x, y, z;
    if (CHFIRST) { x = base[p];   y = base[N + p];   z = base[2*N + p]; }
    else         { x = base[3*p]; y = base[3*p + 1]; z = base[3*p + 2]; }
    float dx = x - qx, dy = y - qy, dz = z - qz;
    float d2 = dx * dx + dy * dy + dz * dz;    // d2 >= 0 -> bits monotone
    uint32_t k = __float_as_uint(d2);
    key[p] = k;
    atomicAdd(&hist[k >> 19], 1u);
  }
  __syncthreads();
  uint32_t ls = 0;
#pragma unroll
  for (int h = 0; h < BPT; ++h) ls += hist[tid * BPT + h];
  uint32_t inc = ls;
#pragma unroll
  for (int off = 1; off < 64; off <<= 1) {
    uint32_t t = __shfl_up(inc, (unsigned)off);
    if (lane >= off) inc += t;
  }
  if (lane == 63) wtot[wid] = inc;
  __syncthreads();
  uint32_t woff = 0;
  for (int w = 0; w < wid; ++w) woff += wtot[w];
  uint32_t excl = inc - ls + woff;
  if (excl < (uint32_t)KNB && excl + ls >= (uint32_t)KNB) {
    uint32_t cum = excl; int bin = tid * BPT;
    while (cum + hist[bin] < (uint32_t)KNB) { cum += hist[bin]; ++bin; }
    sc[0] = bin; sc[1] = (int)cum;
  }
  __syncthreads();
  const uint32_t pivot = (uint32_t)sc[0];
  const int below = sc[1];
  int myc = 0;
  for (int c = 0; c < PPT; ++c) {
    int p = c * NT + tid;
    if ((key[p] >> 19) < pivot) ++myc;
  }
  uint32_t inc2 = (uint32_t)myc;
#pragma unroll
  for (int off = 1; off < 64; off <<= 1) {
    uint32_t t = __shfl_up(inc2, (unsigned)off);
    if (lane >= off) inc2 += t;
  }
  if (lane == 63) wtot[wid] = inc2;
  __syncthreads();
  uint32_t woff2 = 0;
  for (int w = 0; w < wid; ++w) woff2 += wtot[w];
  int off2 = (int)(inc2 - (uint32_t)myc + woff2);
  for (int c = 0; c < PPT; ++c) {
    int p = c * NT + tid;
    if ((key[p] >> 19) < pivot) outq[off2++] = p;
  }
  const int r = KNB - below;
  for (int t = 0; t < r; ++t) {
    __syncthreads();
    uint32_t bk = 0xFFFFFFFFu; int bi = N;
    for (int c = 0; c < PPT; ++c) {
      int p = c * NT + tid;
      uint32_t kk = key[p];
      if ((kk & 0x80000000u) == 0 && (kk >> 19) == pivot) {
        if (kk < bk || (kk == bk && p < bi)) { bk = kk; bi = p; }
      }
    }
#pragma unroll
    for (int o = 32; o > 0; o >>= 1) {
      uint32_t ok = __shfl_xor(bk, o);
      int oi = __shfl_xor(bi, o);
      if (ok < bk || (ok == bk && oi < bi)) { bk = ok; bi = oi; }
    }
    if (lane == 0) { wk[wid] = bk; wi2[wid] = bi; }
    __syncthreads();
    if (tid == 0) {
      uint32_t k0 = wk[0]; int i0 = wi2[0];
      for (int w2 = 1; w2 < NW; ++w2)
        if (wk[w2] < k0 || (wk[w2] == k0 && wi2[w2] < i0)) { k0 = wk[w2]; i0 = wi2[w2]; }
      key[i0] |= 0x80000000u;
      outq[below + t] = i0;
    }
  }
}

// ---------------- fused mid dispatch: fps2 (4 blocks) + knn1 (16384 blocks) ----------------
__global__ __launch_bounds__(512)
void mid_kernel(const float* __restrict__ pc, const float* __restrict__ pc1,
                float* __restrict__ idx2_out, float* __restrict__ pc2,
                float* __restrict__ out1, int* __restrict__ nidx1)
{
  __shared__ __align__(16) char sm[78208];
  const int bid = blockIdx.x;
  if (bid < B_) {
    float4* lpk = (float4*)sm;                                  // 65536
    unsigned short* soid = (unsigned short*)(sm + 65536);       // 8192
    unsigned short* sidx = (unsigned short*)(sm + 73728);       // 4096
    unsigned int* cellc  = (unsigned int*)(sm + 77824);         // 256
    unsigned long long* kq = (unsigned long long*)(sm + 78080); // 128
    fps_body<S1, S2, false>(pc1 + (size_t)bid * S1 * 3, idx2_out + (size_t)bid * S2,
                            pc2 + (size_t)bid * S2 * 3, out1 + (size_t)bid * 3 * S2,
                            lpk, soid, sidx, cellc, kq);
  } else {
    const int idx = bid - B_;
    const int b = idx >> 12;
    const int q = idx & 4095;
    knn_body<512, N0, true>(pc + (size_t)b * 3 * N0,
                            pc1 + ((size_t)b * S1 + q) * 3,
                            nidx1 + ((size_t)b * S1 + q) * KNB, sm, threadIdx.x);
  }
}

// ---------------- block-local stats reduction ----------------
template<int COUT>
__device__ __forceinline__ void block_stats(const float* __restrict__ psum,
                                            const float* __restrict__ psq,
                                            int b, float invcnt,
                                            float* __restrict__ smean,
                                            float* __restrict__ srsv, int tid)
{
  if (tid < COUT) {
    const float* ps = psum + (size_t)b * 512 * COUT + tid;
    const float* pq = psq  + (size_t)b * 512 * COUT + tid;
    float s0 = 0.f, s1 = 0.f, s2 = 0.f, s3 = 0.f;
    float q0 = 0.f, q1 = 0.f, q2 = 0.f, q3 = 0.f;
    for (int k = 0; k < 512; k += 4) {
      s0 += ps[(size_t)(k + 0) * COUT]; q0 += pq[(size_t)(k + 0) * COUT];
      s1 += ps[(size_t)(k + 1) * COUT]; q1 += pq[(size_t)(k + 1) * COUT];
      s2 += ps[(size_t)(k + 2) * COUT]; q2 += pq[(size_t)(k + 2) * COUT];
      s3 += ps[(size_t)(k + 3) * COUT]; q3 += pq[(size_t)(k + 3) * COUT];
    }
    float s = (s0 + s1) + (s2 + s3);
    float q = (q0 + q1) + (q2 + q3);
    float m = s * invcnt;
    float v = q * invcnt - m * m;
    smean[tid] = m;
    srsv[tid] = rsqrtf(fmaxf(v, 0.f) + EPS_IN_);
  }
}

// ---------------- fused stage-1 layer-a linear + knn2 (role-split) ----------------
__global__ __launch_bounds__(256)
void s1a_kernel(const float* __restrict__ pc, const float* __restrict__ feat,
                const int* __restrict__ nidx1, const float* __restrict__ pc1,
                const float* __restrict__ pc2, int* __restrict__ nidx2,
                const float* __restrict__ w, const float* __restrict__ bias,
                __hip_bfloat16* __restrict__ out,
                float* __restrict__ psum, float* __restrict__ psq)
{
  __shared__ __align__(16) char smb[33024];
  const int bx = blockIdx.x, b = blockIdx.y;
  const int co = threadIdx.x, ty = threadIdx.y;
  const int tid = ty * 32 + co;
  if (bx >= 512) {
    const int q = bx - 512;
    knn_body<256, S1, false>(pc1 + (size_t)b * S1 * 3,
                             pc2 + ((size_t)b * S2 + q) * 3,
                             nidx2 + ((size_t)b * S2 + q) * KNB, smb, tid);
    return;
  }
  constexpr int CIN = 6, COUT = 32, TY = 8, EPT = 32, E = TY * EPT;
  float (*xs)[CIN] = (float(*)[CIN])smb;
  float (*r1)[COUT] = (float(*)[COUT])(smb + 6144);
  float (*r2)[COUT] = (float(*)[COUT])(smb + 6144 + 1024);
  {
    int eg = bx * E + tid;
    int s = eg >> 5;
    int n = nidx1[((size_t)b * S1 + s) * KNB + (eg & 31)];
    const float* pb = pc + (size_t)b * 3 * N0;
    const float* fb = feat + (size_t)b * 3 * N0;
    const float* c = pc1 + ((size_t)b * S1 + s) * 3;
    xs[tid][0] = pb[n] - c[0];
    xs[tid][1] = pb[N0 + n] - c[1];
    xs[tid][2] = pb[2 * N0 + n] - c[2];
    xs[tid][3] = fb[n];
    xs[tid][4] = fb[N0 + n];
    xs[tid][5] = fb[2 * N0 + n];
  }
  __syncthreads();
  float wr[CIN];
#pragma unroll
  for (int ci = 0; ci < CIN; ++ci) wr[ci] = w[co * CIN + ci];
  const float bsv = bias[co];
  float ssum = 0.f, ssq = 0.f;
  __hip_bfloat16* ob = out + ((size_t)b * S1 * KNB + (size_t)bx * E) * COUT;
  for (int t = 0; t < EPT; ++t) {
    int e = ty * EPT + t;
    float acc = bsv;
#pragma unroll
    for (int ci = 0; ci < CIN; ++ci) acc += wr[ci] * xs[e][ci];
    ob[(size_t)e * COUT + co] = __float2bfloat16(acc);
    ssum += acc; ssq += acc * acc;
  }
  r1[ty][co] = ssum; r2[ty][co] = ssq;
  __syncthreads();
  if (ty == 0) {
    float a = 0.f, c = 0.f;
#pragma unroll
    for (int y = 0; y < TY; ++y) { a += r1[y][co]; c += r2[y][co]; }
    psum[((size_t)b * 512 + bx) * COUT + co] = a;
    psq [((size_t)b * 512 + bx) * COUT + co] = c;
  }
}

__global__ __launch_bounds__(256)
void lin2a_kernel(const float* __restrict__ pc1, const float* __restrict__ f1,
                  const int* __restrict__ nidx, const float* __restrict__ ctr,
                  const float* __restrict__ w, const float* __restrict__ bias,
                  __hip_bfloat16* __restrict__ out,
                  float* __restrict__ psum, float* __restrict__ psq)
{
  constexpr int CIN = 35, COUT = 64, TY = 4, EPT = 32, E = TY * EPT, NTHR = 256;
  __shared__ float xs[E][CIN];
  __shared__ float r1[TY][COUT], r2[TY][COUT];
  const int co = threadIdx.x, ty = threadIdx.y;
  const int tid = ty * COUT + co;
  const int blk = blockIdx.x, b = blockIdx.y;
  const int eg0 = blk * E;
  for (int v = tid; v < E * CIN; v += NTHR) {
    int e = v / CIN, ci = v - e * CIN;
    int eg = eg0 + e;
    int s = eg >> 5;
    int n = nidx[((size_t)b * S2 + s) * KNB + (eg & 31)];
    float val;
    if (ci < 3) val = pc1[((size_t)b * S1 + n) * 3 + ci] - ctr[((size_t)b * S2 + s) * 3 + ci];
    else        val = f1[((size_t)b * S1 + n) * 32 + (ci - 3)];
    xs[e][ci] = val;
  }
  __syncthreads();
  float wr[CIN];
#pragma unroll
  for (int ci = 0; ci < CIN; ++ci) wr[ci] = w[co * CIN + ci];
  const float bsv = bias[co];
  float ssum = 0.f, ssq = 0.f;
  __hip_bfloat16* ob = out + ((size_t)b * S2 * KNB + (size_t)eg0) * COUT;
  for (int t = 0; t < EPT; ++t) {
    int e = ty * EPT + t;
    float acc = bsv;
#pragma unroll
    for (int ci = 0; ci < CIN; ++ci) acc += wr[ci] * xs[e][ci];
    ob[(size_t)e * COUT + co] = __float2bfloat16(acc);
    ssum += acc; ssq += acc * acc;
  }
  r1[ty][co] = ssum; r2[ty][co] = ssq;
  __syncthreads();
  if (ty == 0) {
    float a = 0.f, c = 0.f;
#pragma unroll
    for (int y = 0; y < TY; ++y) { a += r1[y][co]; c += r2[y][co]; }
    psum[((size_t)b * 512 + blk) * COUT + co] = a;
    psq [((size_t)b * 512 + blk) * COUT + co] = c;
  }
}

// ---------------- linear with fused input-stats+norm+relu (layers b, c) ----------------
template<int CIN, int COUT, int TY, int EPT>
__global__ __launch_bounds__(COUT * TY)
void linear_norm_kernel(const __hip_bfloat16* __restrict__ x,
                        const float* __restrict__ psum_in, const float* __restrict__ psq_in,
                        float invcnt,
                        const float* __restrict__ w, const float* __restrict__ bias,
                        __hip_bfloat16* __restrict__ out,
                        float* __restrict__ psum, float* __restrict__ psq, int elems)
{
  constexpr int NTHR = COUT * TY;
  constexpr int E = TY * EPT;
  __shared__ float xs[E][CIN];
  __shared__ float sm_[CIN], sr_[CIN];
  __shared__ float r1[TY][COUT], r2[TY][COUT];
  const int co = threadIdx.x, ty = threadIdx.y;
  const int tid = ty * COUT + co;
  const int blk = blockIdx.x, b = blockIdx.y;
  block_stats<CIN>(psum_in, psq_in, b, invcnt, sm_, sr_, tid);
  const int e0 = blk * E;
  const __hip_bfloat16* xb = x + ((size_t)b * elems + e0) * CIN;
  __syncthreads();
  for (int v = tid; v < E * CIN; v += NTHR) {
    int e = v / CIN, ci = v - (v / CIN) * CIN;
    float val = __bfloat162float(xb[v]);
    xs[e][ci] = fmaxf(0.f, (val - sm_[ci]) * sr_[ci]);
  }
  __syncthreads();
  float wr[CIN];
#pragma unroll
  for (int ci = 0; ci < CIN; ++ci) wr[ci] = w[co * CIN + ci];
  const float bsv = bias[co];
  float ssum = 0.f, ssq = 0.f;
  __hip_bfloat16* ob = out + ((size_t)b * elems + e0) * COUT;
  for (int t = 0; t < EPT; ++t) {
    int e = ty * EPT + t;
    float acc = bsv;
#pragma unroll
    for (int ci = 0; ci < CIN; ++ci) acc += wr[ci] * xs[e][ci];
    ob[(size_t)e * COUT + co] = __float2bfloat16(acc);
    ssum += acc; ssq += acc * acc;
  }
  r1[ty][co] = ssum; r2[ty][co] = ssq;
  __syncthreads();
  if (ty == 0) {
    float a = 0.f, c = 0.f;
#pragma unroll
    for (int y = 0; y < TY; ++y) { a += r1[y][co]; c += r2[y][co]; }
    psum[((size_t)b * 512 + blk) * COUT + co] = a;
    psq [((size_t)b * 512 + blk) * COUT + co] = c;
  }
}

// ---------------- max-pool with fused stats + final norm+relu ----------------
__global__ __launch_bounds__(256)
void pool1_kernel(const __hip_bfloat16* __restrict__ buf,
                  const float* __restrict__ psum_in, const float* __restrict__ psq_in,
                  float invcnt, float* __restrict__ f1)
{
  __shared__ float smean[32], srsv[32];
  const int tid = threadIdx.x;
  const int b = blockIdx.y;
  block_stats<32>(psum_in, psq_in, b, invcnt, smean, srsv, tid);
  __syncthreads();
  int i = blockIdx.x * 256 + tid;
  if (i >= S1 * 32) return;
  int s = i >> 5, co = i & 31;
  const __hip_bfloat16* bb = buf + ((size_t)b * S1 * KNB + (size_t)s * KNB) * 32 + co;
  float best = -3.4e38f;
  for (int j = 0; j < KNB; ++j) best = fmaxf(best, __bfloat162float(bb[j * 32]));
  best = fmaxf(0.f, (best - smean[co]) * srsv[co]);
  f1[((size_t)b * S1 + s) * 32 + co] = best;
}

__global__ __launch_bounds__(256)
void pool2_kernel(const __hip_bfloat16* __restrict__ buf,
                  const float* __restrict__ psum_in, const float* __restrict__ psq_in,
                  float invcnt, float* __restrict__ out2)
{
  __shared__ float smean[64], srsv[64];
  const int tid = threadIdx.x;
  const int b = blockIdx.y;
  block_stats<64>(psum_in, psq_in, b, invcnt, smean, srsv, tid);
  __syncthreads();
  int i = blockIdx.x * 256 + tid;
  if (i >= S2 * 64) return;
  int s = i >> 6, co = i & 63;
  const __hip_bfloat16* bb = buf + ((size_t)b * S2 * KNB + (size_t)s * KNB) * 64 + co;
  float best = -3.4e38f;
  for (int j = 0; j < KNB; ++j) best = fmaxf(best, __bfloat162float(bb[j * 64]));
  best = fmaxf(0.f, (best - smean[co]) * srsv[co]);
  out2[((size_t)b * 64 + co) * S2 + s] = best;   // [B,64,S2] transposed
}

extern "C" void kernel_launch(void* const* d_in, const int* in_sizes, int n_in,
                              void* d_out, int out_size, void* d_ws, size_t ws_size,
                              hipStream_t stream)
{
  (void)in_sizes; (void)n_in; (void)out_size; (void)ws_size;
  const float* pc   = (const float*)d_in[0];
  const float* feat = (const float*)d_in[1];
  const float* w1a = (const float*)d_in[2];  const float* b1a = (const float*)d_in[3];
  const float* w1b = (const float*)d_in[4];  const float* b1b = (const float*)d_in[5];
  const float* w1c = (const float*)d_in[6];  const float* b1c = (const float*)d_in[7];
  const float* w2a = (const float*)d_in[8];  const float* b2a = (const float*)d_in[9];
  const float* w2b = (const float*)d_in[10]; const float* b2b = (const float*)d_in[11];
  const float* w2c = (const float*)d_in[12]; const float* b2c = (const float*)d_in[13];

  float* out  = (float*)d_out;
  float* out0 = out;                 // pc1^T [4,3,4096]
  float* out1 = out + 49152;         // pc2^T [4,3,2048]
  float* out2 = out + 73728;         // f2^T  [4,64,2048]
  float* out3 = out + 598016;        // idx1  [4,4096] (as float)
  float* out4 = out + 614400;        // idx2  [4,2048] (as float)

  char* wp = (char*)d_ws;
  auto carve = [&](size_t bytes) { char* p = wp; wp += (bytes + 255) & ~(size_t)255; return p; };
  __hip_bfloat16* bufA = (__hip_bfloat16*)carve((size_t)B_ * S1 * KNB * 32 * 2);
  __hip_bfloat16* bufB = (__hip_bfloat16*)carve((size_t)B_ * S1 * KNB * 32 * 2);
  int*   nidx1 = (int*)carve((size_t)B_ * S1 * KNB * 4);
  int*   nidx2 = (int*)carve((size_t)B_ * S2 * KNB * 4);
  float* pc1   = (float*)carve((size_t)B_ * S1 * 3 * 4);
  float* pc2   = (float*)carve((size_t)B_ * S2 * 3 * 4);
  float* f1    = (float*)carve((size_t)B_ * S1 * 32 * 4);
  float* psum0 = (float*)carve((size_t)B_ * 512 * 64 * 4);
  float* psq0  = (float*)carve((size_t)B_ * 512 * 64 * 4);
  float* psum1 = (float*)carve((size_t)B_ * 512 * 64 * 4);
  float* psq1  = (float*)carve((size_t)B_ * 512 * 64 * 4);

  const float ic1 = 1.f / (S1 * KNB);
  const float ic2 = 1.f / (S2 * KNB);

  // ---- stage 1 ----
  fps_kernel<N0, S1, true><<<B_, 512, 0, stream>>>(pc, out3, pc1, out0);
  mid_kernel<<<B_ + S1 * B_, 512, 0, stream>>>(pc, pc1, out4, pc2, out1, nidx1);
  s1a_kernel<<<dim3(2560, B_), dim3(32, 8), 0, stream>>>(pc, feat, nidx1, pc1, pc2, nidx2,
                                                         w1a, b1a, bufA, psum0, psq0);
  linear_norm_kernel<32, 32, 8, 32><<<dim3(512, B_), dim3(32, 8), 0, stream>>>(
      bufA, psum0, psq0, ic1, w1b, b1b, bufB, psum1, psq1, S1 * KNB);
  linear_norm_kernel<32, 32, 8, 32><<<dim3(512, B_), dim3(32, 8), 0, stream>>>(
      bufB, psum1, psq1, ic1, w1c, b1c, bufA, psum0, psq0, S1 * KNB);
  pool1_kernel<<<dim3(512, B_), 256, 0, stream>>>(bufA, psum0, psq0, ic1, f1);

  // ---- stage 2 ----
  lin2a_kernel<<<dim3(512, B_), dim3(64, 4), 0, stream>>>(pc1, f1, nidx2, pc2,
                                                          w2a, b2a, bufB, psum1, psq1);
  linear_norm_kernel<64, 64, 4, 32><<<dim3(512, B_), dim3(64, 4), 0, stream>>>(
      bufB, psum1, psq1, ic2, w2b, b2b, bufA, psum0, psq0, S2 * KNB);
  linear_norm_kernel<64, 64, 4, 32><<<dim3(512, B_), dim3(64, 4), 0, stream>>>(
      bufA, psum0, psq0, ic2, w2c, b2c, bufB, psum1, psq1, S2 * KNB);
  pool2_kernel<<<dim3(512, B_), 256, 0, stream>>>(bufB, psum1, psq1, ic2, out2);
}

// Round 14
// 5878.898 us; speedup vs baseline: 1.0904x; 1.0904x over previous
//
#include <hip/hip_runtime.h>
#include <hip/hip_bf16.h>
#include <stdint.h>

#define B_  4
#define N0  8192
#define S1  4096
#define S2  2048
#define KNB 32

static constexpr float EPS_IN_ = 1e-5f;

// ---------------- FPS body (golden index path — EXACT round-9 code, frozen) ----------------
// d2 must match numpy exactly: (dx*dx + dy*dy) + dz*dz, all round-nearest,
// NO FMA contraction -> `#pragma clang fp contract(off)`. DPP wave argmax
// (f32 max + i32 min among maxers), u64 key per wave, ONE barrier/iter.
// NOTE (rounds 6,10,11,13): pruning/packing/ballot variants all regressed;
// this structure is the measured local optimum (~2350 cyc/iter, 81% VALU).
template<int N, int NP, bool CHFIRST>
__device__ __forceinline__ void fps_body(
    const float* __restrict__ base, float* __restrict__ fidx_out,
    float* __restrict__ newxyz, float* __restrict__ out_t,
    float4* __restrict__ lpk, unsigned long long* __restrict__ kq,
    int* __restrict__ sidx)
{
  constexpr int NT = 512;
  constexpr int PPT = N / NT;
  const int tid = threadIdx.x;
  const int lane = tid & 63;
  const int wid = tid >> 6;

  float px[PPT], py[PPT], pz[PPT], dist[PPT];
#pragma unroll
  for (int j = 0; j < PPT; ++j) {
    int p = tid + j * NT;
    float x, y, z;
    if (CHFIRST) { x = base[p];   y = base[N + p];   z = base[2*N + p]; }
    else         { x = base[3*p]; y = base[3*p + 1]; z = base[3*p + 2]; }
    px[j] = x; py[j] = y; pz[j] = z;
    lpk[p] = make_float4(x, y, z, 0.f);
    dist[j] = 1e10f;
  }
  if (tid == 0) sidx[0] = 0;
  __syncthreads();
  float bx = lpk[0].x, by = lpk[0].y, bz = lpk[0].z;

  for (int i = 1; i < NP; ++i) {
    const int par = i & 1;
    float bv = -1.f; int bi = 0;
#pragma unroll
    for (int j = 0; j < PPT; ++j) {
#pragma clang fp contract(off)
      float dx = px[j] - bx;
      float dy = py[j] - by;
      float dz = pz[j] - bz;
      float d2 = (dx * dx + dy * dy) + dz * dz;   // strict numpy order, no FMA
      float nd = fminf(dist[j], d2);
      dist[j] = nd;
      if (nd > bv) { bv = nd; bi = tid + (j << 9); }
    }
    {
      int x = __float_as_int(bv), t;
      t = __builtin_amdgcn_update_dpp(0, x, 0x111, 0xf, 0xf, false);
      x = __float_as_int(fmaxf(__int_as_float(x), __int_as_float(t)));
      t = __builtin_amdgcn_update_dpp(0, x, 0x112, 0xf, 0xf, false);
      x = __float_as_int(fmaxf(__int_as_float(x), __int_as_float(t)));
      t = __builtin_amdgcn_update_dpp(0, x, 0x114, 0xf, 0xf, false);
      x = __float_as_int(fmaxf(__int_as_float(x), __int_as_float(t)));
      t = __builtin_amdgcn_update_dpp(0, x, 0x118, 0xf, 0xf, false);
      x = __float_as_int(fmaxf(__int_as_float(x), __int_as_float(t)));
      t = __builtin_amdgcn_update_dpp(0, x, 0x142, 0xa, 0xf, false);
      x = __float_as_int(fmaxf(__int_as_float(x), __int_as_float(t)));
      t = __builtin_amdgcn_update_dpp(0, x, 0x143, 0xc, 0xf, false);
      x = __float_as_int(fmaxf(__int_as_float(x), __int_as_float(t)));
      const int wmax_bits = __builtin_amdgcn_readlane(x, 63);
      int m = (__float_as_int(bv) == wmax_bits) ? bi : 0x7fffffff;
      t = __builtin_amdgcn_update_dpp(0x7fffffff, m, 0x111, 0xf, 0xf, false);
      m = min(m, t);
      t = __builtin_amdgcn_update_dpp(0x7fffffff, m, 0x112, 0xf, 0xf, false);
      m = min(m, t);
      t = __builtin_amdgcn_update_dpp(0x7fffffff, m, 0x114, 0xf, 0xf, false);
      m = min(m, t);
      t = __builtin_amdgcn_update_dpp(0x7fffffff, m, 0x118, 0xf, 0xf, false);
      m = min(m, t);
      t = __builtin_amdgcn_update_dpp(0x7fffffff, m, 0x142, 0xa, 0xf, false);
      m = min(m, t);
      t = __builtin_amdgcn_update_dpp(0x7fffffff, m, 0x143, 0xc, 0xf, false);
      m = min(m, t);
      const int widx = __builtin_amdgcn_readlane(m, 63);
      if (lane == 0)
        kq[par * 8 + wid] = ((unsigned long long)(unsigned)wmax_bits << 32) |
                            (uint32_t)(~(uint32_t)widx);
    }
    __syncthreads();
    unsigned long long g = kq[par * 8 + 0];
#pragma unroll
    for (int w = 1; w < 8; ++w) {
      unsigned long long t2 = kq[par * 8 + w];
      g = (t2 > g) ? t2 : g;
    }
    const int wi = (int)(~(uint32_t)g);
    float4 c = lpk[wi];
    bx = c.x; by = c.y; bz = c.z;
    if (tid == 0) sidx[i] = wi;
  }
  __syncthreads();
  for (int s = tid; s < NP; s += NT) {
    int id = sidx[s];
    float4 c = lpk[id];
    fidx_out[s] = (float)id;
    newxyz[s * 3 + 0] = c.x;
    newxyz[s * 3 + 1] = c.y;
    newxyz[s * 3 + 2] = c.z;
    out_t[s] = c.x; out_t[NP + s] = c.y; out_t[2 * NP + s] = c.z;
  }
}

template<int N, int NP, bool CHFIRST>
__global__ __launch_bounds__(512)
void fps_kernel(const float* __restrict__ pts, float* __restrict__ fidx_out,
                float* __restrict__ newxyz, float* __restrict__ out_t)
{
  __shared__ float4 lpk[N];
  __shared__ unsigned long long kq[16];
  __shared__ int sidx[NP];
  const int b = blockIdx.x;
  fps_body<N, NP, CHFIRST>(pts + (size_t)b * 3 * N, fidx_out + (size_t)b * NP,
                           newxyz + (size_t)b * NP * 3, out_t + (size_t)b * 3 * NP,
                           lpk, kq, sidx);
}

// ---------------- exact kNN body (NT-generic, parallel scans) ----------------
template<int NT, int N, bool CHFIRST>
__device__ __forceinline__ void knn_body(const float* __restrict__ base,
                                         const float* __restrict__ qp,
                                         int* __restrict__ outq, char* __restrict__ sm,
                                         int tid)
{
  constexpr int PPT = N / NT;
  constexpr int NW = NT / 64;
  constexpr int HB = 4096;
  constexpr int BPT = HB / NT;
  const int lane = tid & 63, wid = tid >> 6;

  uint32_t* key  = (uint32_t*)sm;
  uint32_t* hist = key + N;
  uint32_t* wtot = hist + HB;
  uint32_t* wk   = wtot + NW;
  int*      wi2  = (int*)(wk + NW);
  int*      sc   = wi2 + NW;

  const float qx = qp[0], qy = qp[1], qz = qp[2];
  for (int h = tid; h < HB; h += NT) hist[h] = 0;
  __syncthreads();
  for (int c = 0; c < PPT; ++c) {
    int p = c * NT + tid;
    float x, y, z;
    if (CHFIRST) { x = base[p];   y = base[N + p];   z = base[2*N + p]; }
    else         { x = base[3*p]; y = base[3*p + 1]; z = base[3*p + 2]; }
    float dx = x - qx, dy = y - qy, dz = z - qz;
    float d2 = dx * dx + dy * dy + dz * dz;    // d2 >= 0 -> bits monotone
    uint32_t k = __float_as_uint(d2);
    key[p] = k;
    atomicAdd(&hist[k >> 19], 1u);
  }
  __syncthreads();
  uint32_t ls = 0;
#pragma unroll
  for (int h = 0; h < BPT; ++h) ls += hist[tid * BPT + h];
  uint32_t inc = ls;
#pragma unroll
  for (int off = 1; off < 64; off <<= 1) {
    uint32_t t = __shfl_up(inc, (unsigned)off);
    if (lane >= off) inc += t;
  }
  if (lane == 63) wtot[wid] = inc;
  __syncthreads();
  uint32_t woff = 0;
  for (int w = 0; w < wid; ++w) woff += wtot[w];
  uint32_t excl = inc - ls + woff;
  if (excl < (uint32_t)KNB && excl + ls >= (uint32_t)KNB) {
    uint32_t cum = excl; int bin = tid * BPT;
    while (cum + hist[bin] < (uint32_t)KNB) { cum += hist[bin]; ++bin; }
    sc[0] = bin; sc[1] = (int)cum;
  }
  __syncthreads();
  const uint32_t pivot = (uint32_t)sc[0];
  const int below = sc[1];
  int myc = 0;
  for (int c = 0; c < PPT; ++c) {
    int p = c * NT + tid;
    if ((key[p] >> 19) < pivot) ++myc;
  }
  uint32_t inc2 = (uint32_t)myc;
#pragma unroll
  for (int off = 1; off < 64; off <<= 1) {
    uint32_t t = __shfl_up(inc2, (unsigned)off);
    if (lane >= off) inc2 += t;
  }
  if (lane == 63) wtot[wid] = inc2;
  __syncthreads();
  uint32_t woff2 = 0;
  for (int w = 0; w < wid; ++w) woff2 += wtot[w];
  int off2 = (int)(inc2 - (uint32_t)myc + woff2);
  for (int c = 0; c < PPT; ++c) {
    int p = c * NT + tid;
    if ((key[p] >> 19) < pivot) outq[off2++] = p;
  }
  const int r = KNB - below;
  for (int t = 0; t < r; ++t) {
    __syncthreads();
    uint32_t bk = 0xFFFFFFFFu; int bi = N;
    for (int c = 0; c < PPT; ++c) {
      int p = c * NT + tid;
      uint32_t kk = key[p];
      if ((kk & 0x80000000u) == 0 && (kk >> 19) == pivot) {
        if (kk < bk || (kk == bk && p < bi)) { bk = kk; bi = p; }
      }
    }
#pragma unroll
    for (int o = 32; o > 0; o >>= 1) {
      uint32_t ok = __shfl_xor(bk, o);
      int oi = __shfl_xor(bi, o);
      if (ok < bk || (ok == bk && oi < bi)) { bk = ok; bi = oi; }
    }
    if (lane == 0) { wk[wid] = bk; wi2[wid] = bi; }
    __syncthreads();
    if (tid == 0) {
      uint32_t k0 = wk[0]; int i0 = wi2[0];
      for (int w2 = 1; w2 < NW; ++w2)
        if (wk[w2] < k0 || (wk[w2] == k0 && wi2[w2] < i0)) { k0 = wk[w2]; i0 = wi2[w2]; }
      key[i0] |= 0x80000000u;
      outq[below + t] = i0;
    }
  }
}

// ---------------- fused mid dispatch: fps2 (4 blocks) + knn1 (16384 blocks) ----------------
__global__ __launch_bounds__(512)
void mid_kernel(const float* __restrict__ pc, const float* __restrict__ pc1,
                float* __restrict__ idx2_out, float* __restrict__ pc2,
                float* __restrict__ out1, int* __restrict__ nidx1)
{
  __shared__ __align__(16) char sm[73856];
  const int bid = blockIdx.x;
  if (bid < B_) {
    float4* lpk = (float4*)sm;
    unsigned long long* kq = (unsigned long long*)(sm + 65536);
    int* sidx = (int*)(sm + 65536 + 128);
    fps_body<S1, S2, false>(pc1 + (size_t)bid * S1 * 3, idx2_out + (size_t)bid * S2,
                            pc2 + (size_t)bid * S2 * 3, out1 + (size_t)bid * 3 * S2,
                            lpk, kq, sidx);
  } else {
    const int idx = bid - B_;
    const int b = idx >> 12;
    const int q = idx & 4095;
    knn_body<512, N0, true>(pc + (size_t)b * 3 * N0,
                            pc1 + ((size_t)b * S1 + q) * 3,
                            nidx1 + ((size_t)b * S1 + q) * KNB, sm, threadIdx.x);
  }
}

// ---------------- block-local stats reduction (replaces stats_kernel) ----------------
template<int COUT>
__device__ __forceinline__ void block_stats(const float* __restrict__ psum,
                                            const float* __restrict__ psq,
                                            int b, float invcnt,
                                            float* __restrict__ smean,
                                            float* __restrict__ srsv, int tid)
{
  if (tid < COUT) {
    const float* ps = psum + (size_t)b * 512 * COUT + tid;
    const float* pq = psq  + (size_t)b * 512 * COUT + tid;
    float s0 = 0.f, s1 = 0.f, s2 = 0.f, s3 = 0.f;
    float q0 = 0.f, q1 = 0.f, q2 = 0.f, q3 = 0.f;
    for (int k = 0; k < 512; k += 4) {
      s0 += ps[(size_t)(k + 0) * COUT]; q0 += pq[(size_t)(k + 0) * COUT];
      s1 += ps[(size_t)(k + 1) * COUT]; q1 += pq[(size_t)(k + 1) * COUT];
      s2 += ps[(size_t)(k + 2) * COUT]; q2 += pq[(size_t)(k + 2) * COUT];
      s3 += ps[(size_t)(k + 3) * COUT]; q3 += pq[(size_t)(k + 3) * COUT];
    }
    float s = (s0 + s1) + (s2 + s3);
    float q = (q0 + q1) + (q2 + q3);
    float m = s * invcnt;
    float v = q * invcnt - m * m;
    smean[tid] = m;
    srsv[tid] = rsqrtf(fmaxf(v, 0.f) + EPS_IN_);
  }
}

// ---------------- fused stage-1 layer-a linear + knn2 (role-split) ----------------
__global__ __launch_bounds__(256)
void s1a_kernel(const float* __restrict__ pc, const float* __restrict__ feat,
                const int* __restrict__ nidx1, const float* __restrict__ pc1,
                const float* __restrict__ pc2, int* __restrict__ nidx2,
                const float* __restrict__ w, const float* __restrict__ bias,
                __hip_bfloat16* __restrict__ out,
                float* __restrict__ psum, float* __restrict__ psq)
{
  __shared__ __align__(16) char smb[33024];
  const int bx = blockIdx.x, b = blockIdx.y;
  const int co = threadIdx.x, ty = threadIdx.y;
  const int tid = ty * 32 + co;
  if (bx >= 512) {
    // knn2 role: queries pc2 against pc1 (row-major), exact 32-NN
    const int q = bx - 512;
    knn_body<256, S1, false>(pc1 + (size_t)b * S1 * 3,
                             pc2 + ((size_t)b * S2 + q) * 3,
                             nidx2 + ((size_t)b * S2 + q) * KNB, smb, tid);
    return;
  }
  // lin1a role (identical math to round-9 lin1a)
  constexpr int CIN = 6, COUT = 32, TY = 8, EPT = 32, E = TY * EPT;
  float (*xs)[CIN] = (float(*)[CIN])smb;                       // 6144 B
  float (*r1)[COUT] = (float(*)[COUT])(smb + 6144);            // 1024 B
  float (*r2)[COUT] = (float(*)[COUT])(smb + 6144 + 1024);     // 1024 B
  {
    int eg = bx * E + tid;
    int s = eg >> 5;
    int n = nidx1[((size_t)b * S1 + s) * KNB + (eg & 31)];
    const float* pb = pc + (size_t)b * 3 * N0;
    const float* fb = feat + (size_t)b * 3 * N0;
    const float* c = pc1 + ((size_t)b * S1 + s) * 3;
    xs[tid][0] = pb[n] - c[0];
    xs[tid][1] = pb[N0 + n] - c[1];
    xs[tid][2] = pb[2 * N0 + n] - c[2];
    xs[tid][3] = fb[n];
    xs[tid][4] = fb[N0 + n];
    xs[tid][5] = fb[2 * N0 + n];
  }
  __syncthreads();
  float wr[CIN];
#pragma unroll
  for (int ci = 0; ci < CIN; ++ci) wr[ci] = w[co * CIN + ci];
  const float bsv = bias[co];
  float ssum = 0.f, ssq = 0.f;
  __hip_bfloat16* ob = out + ((size_t)b * S1 * KNB + (size_t)bx * E) * COUT;
  for (int t = 0; t < EPT; ++t) {
    int e = ty * EPT + t;
    float acc = bsv;
#pragma unroll
    for (int ci = 0; ci < CIN; ++ci) acc += wr[ci] * xs[e][ci];
    ob[(size_t)e * COUT + co] = __float2bfloat16(acc);
    ssum += acc; ssq += acc * acc;
  }
  r1[ty][co] = ssum; r2[ty][co] = ssq;
  __syncthreads();
  if (ty == 0) {
    float a = 0.f, c = 0.f;
#pragma unroll
    for (int y = 0; y < TY; ++y) { a += r1[y][co]; c += r2[y][co]; }
    psum[((size_t)b * 512 + bx) * COUT + co] = a;
    psq [((size_t)b * 512 + bx) * COUT + co] = c;
  }
}

__global__ __launch_bounds__(256)
void lin2a_kernel(const float* __restrict__ pc1, const float* __restrict__ f1,
                  const int* __restrict__ nidx, const float* __restrict__ ctr,
                  const float* __restrict__ w, const float* __restrict__ bias,
                  __hip_bfloat16* __restrict__ out,
                  float* __restrict__ psum, float* __restrict__ psq)
{
  constexpr int CIN = 35, COUT = 64, TY = 4, EPT = 32, E = TY * EPT, NTHR = 256;
  __shared__ float xs[E][CIN];
  __shared__ float r1[TY][COUT], r2[TY][COUT];
  const int co = threadIdx.x, ty = threadIdx.y;
  const int tid = ty * COUT + co;
  const int blk = blockIdx.x, b = blockIdx.y;
  const int eg0 = blk * E;
  for (int v = tid; v < E * CIN; v += NTHR) {
    int e = v / CIN, ci = v - e * CIN;
    int eg = eg0 + e;
    int s = eg >> 5;
    int n = nidx[((size_t)b * S2 + s) * KNB + (eg & 31)];
    float val;
    if (ci < 3) val = pc1[((size_t)b * S1 + n) * 3 + ci] - ctr[((size_t)b * S2 + s) * 3 + ci];
    else        val = f1[((size_t)b * S1 + n) * 32 + (ci - 3)];
    xs[e][ci] = val;
  }
  __syncthreads();
  float wr[CIN];
#pragma unroll
  for (int ci = 0; ci < CIN; ++ci) wr[ci] = w[co * CIN + ci];
  const float bsv = bias[co];
  float ssum = 0.f, ssq = 0.f;
  __hip_bfloat16* ob = out + ((size_t)b * S2 * KNB + (size_t)eg0) * COUT;
  for (int t = 0; t < EPT; ++t) {
    int e = ty * EPT + t;
    float acc = bsv;
#pragma unroll
    for (int ci = 0; ci < CIN; ++ci) acc += wr[ci] * xs[e][ci];
    ob[(size_t)e * COUT + co] = __float2bfloat16(acc);
    ssum += acc; ssq += acc * acc;
  }
  r1[ty][co] = ssum; r2[ty][co] = ssq;
  __syncthreads();
  if (ty == 0) {
    float a = 0.f, c = 0.f;
#pragma unroll
    for (int y = 0; y < TY; ++y) { a += r1[y][co]; c += r2[y][co]; }
    psum[((size_t)b * 512 + blk) * COUT + co] = a;
    psq [((size_t)b * 512 + blk) * COUT + co] = c;
  }
}

// ---------------- linear with fused input-stats+norm+relu (layers b, c) ----------------
template<int CIN, int COUT, int TY, int EPT>
__global__ __launch_bounds__(COUT * TY)
void linear_norm_kernel(const __hip_bfloat16* __restrict__ x,
                        const float* __restrict__ psum_in, const float* __restrict__ psq_in,
                        float invcnt,
                        const float* __restrict__ w, const float* __restrict__ bias,
                        __hip_bfloat16* __restrict__ out,
                        float* __restrict__ psum, float* __restrict__ psq, int elems)
{
  constexpr int NTHR = COUT * TY;
  constexpr int E = TY * EPT;
  __shared__ float xs[E][CIN];
  __shared__ float sm_[CIN], sr_[CIN];
  __shared__ float r1[TY][COUT], r2[TY][COUT];
  const int co = threadIdx.x, ty = threadIdx.y;
  const int tid = ty * COUT + co;
  const int blk = blockIdx.x, b = blockIdx.y;
  block_stats<CIN>(psum_in, psq_in, b, invcnt, sm_, sr_, tid);
  const int e0 = blk * E;
  const __hip_bfloat16* xb = x + ((size_t)b * elems + e0) * CIN;
  __syncthreads();
  for (int v = tid; v < E * CIN; v += NTHR) {
    int e = v / CIN, ci = v - (v / CIN) * CIN;
    float val = __bfloat162float(xb[v]);
    xs[e][ci] = fmaxf(0.f, (val - sm_[ci]) * sr_[ci]);
  }
  __syncthreads();
  float wr[CIN];
#pragma unroll
  for (int ci = 0; ci < CIN; ++ci) wr[ci] = w[co * CIN + ci];
  const float bsv = bias[co];
  float ssum = 0.f, ssq = 0.f;
  __hip_bfloat16* ob = out + ((size_t)b * elems + e0) * COUT;
  for (int t = 0; t < EPT; ++t) {
    int e = ty * EPT + t;
    float acc = bsv;
#pragma unroll
    for (int ci = 0; ci < CIN; ++ci) acc += wr[ci] * xs[e][ci];
    ob[(size_t)e * COUT + co] = __float2bfloat16(acc);
    ssum += acc; ssq += acc * acc;
  }
  r1[ty][co] = ssum; r2[ty][co] = ssq;
  __syncthreads();
  if (ty == 0) {
    float a = 0.f, c = 0.f;
#pragma unroll
    for (int y = 0; y < TY; ++y) { a += r1[y][co]; c += r2[y][co]; }
    psum[((size_t)b * 512 + blk) * COUT + co] = a;
    psq [((size_t)b * 512 + blk) * COUT + co] = c;
  }
}

// ---------------- max-pool with fused stats + final norm+relu ----------------
__global__ __launch_bounds__(256)
void pool1_kernel(const __hip_bfloat16* __restrict__ buf,
                  const float* __restrict__ psum_in, const float* __restrict__ psq_in,
                  float invcnt, float* __restrict__ f1)
{
  __shared__ float smean[32], srsv[32];
  const int tid = threadIdx.x;
  const int b = blockIdx.y;
  block_stats<32>(psum_in, psq_in, b, invcnt, smean, srsv, tid);
  __syncthreads();
  int i = blockIdx.x * 256 + tid;
  if (i >= S1 * 32) return;
  int s = i >> 5, co = i & 31;
  const __hip_bfloat16* bb = buf + ((size_t)b * S1 * KNB + (size_t)s * KNB) * 32 + co;
  float best = -3.4e38f;
  for (int j = 0; j < KNB; ++j) best = fmaxf(best, __bfloat162float(bb[j * 32]));
  best = fmaxf(0.f, (best - smean[co]) * srsv[co]);
  f1[((size_t)b * S1 + s) * 32 + co] = best;
}

__global__ __launch_bounds__(256)
void pool2_kernel(const __hip_bfloat16* __restrict__ buf,
                  const float* __restrict__ psum_in, const float* __restrict__ psq_in,
                  float invcnt, float* __restrict__ out2)
{
  __shared__ float smean[64], srsv[64];
  const int tid = threadIdx.x;
  const int b = blockIdx.y;
  block_stats<64>(psum_in, psq_in, b, invcnt, smean, srsv, tid);
  __syncthreads();
  int i = blockIdx.x * 256 + tid;
  if (i >= S2 * 64) return;
  int s = i >> 6, co = i & 63;
  const __hip_bfloat16* bb = buf + ((size_t)b * S2 * KNB + (size_t)s * KNB) * 64 + co;
  float best = -3.4e38f;
  for (int j = 0; j < KNB; ++j) best = fmaxf(best, __bfloat162float(bb[j * 64]));
  best = fmaxf(0.f, (best - smean[co]) * srsv[co]);
  out2[((size_t)b * 64 + co) * S2 + s] = best;   // [B,64,S2] transposed
}

extern "C" void kernel_launch(void* const* d_in, const int* in_sizes, int n_in,
                              void* d_out, int out_size, void* d_ws, size_t ws_size,
                              hipStream_t stream)
{
  (void)in_sizes; (void)n_in; (void)out_size; (void)ws_size;
  const float* pc   = (const float*)d_in[0];
  const float* feat = (const float*)d_in[1];
  const float* w1a = (const float*)d_in[2];  const float* b1a = (const float*)d_in[3];
  const float* w1b = (const float*)d_in[4];  const float* b1b = (const float*)d_in[5];
  const float* w1c = (const float*)d_in[6];  const float* b1c = (const float*)d_in[7];
  const float* w2a = (const float*)d_in[8];  const float* b2a = (const float*)d_in[9];
  const float* w2b = (const float*)d_in[10]; const float* b2b = (const float*)d_in[11];
  const float* w2c = (const float*)d_in[12]; const float* b2c = (const float*)d_in[13];

  float* out  = (float*)d_out;
  float* out0 = out;                 // pc1^T [4,3,4096]
  float* out1 = out + 49152;         // pc2^T [4,3,2048]
  float* out2 = out + 73728;         // f2^T  [4,64,2048]
  float* out3 = out + 598016;        // idx1  [4,4096] (as float)
  float* out4 = out + 614400;        // idx2  [4,2048] (as float)

  char* wp = (char*)d_ws;
  auto carve = [&](size_t bytes) { char* p = wp; wp += (bytes + 255) & ~(size_t)255; return p; };
  __hip_bfloat16* bufA = (__hip_bfloat16*)carve((size_t)B_ * S1 * KNB * 32 * 2);
  __hip_bfloat16* bufB = (__hip_bfloat16*)carve((size_t)B_ * S1 * KNB * 32 * 2);
  int*   nidx1 = (int*)carve((size_t)B_ * S1 * KNB * 4);
  int*   nidx2 = (int*)carve((size_t)B_ * S2 * KNB * 4);
  float* pc1   = (float*)carve((size_t)B_ * S1 * 3 * 4);
  float* pc2   = (float*)carve((size_t)B_ * S2 * 3 * 4);
  float* f1    = (float*)carve((size_t)B_ * S1 * 32 * 4);
  float* psum0 = (float*)carve((size_t)B_ * 512 * 64 * 4);
  float* psq0  = (float*)carve((size_t)B_ * 512 * 64 * 4);
  float* psum1 = (float*)carve((size_t)B_ * 512 * 64 * 4);
  float* psq1  = (float*)carve((size_t)B_ * 512 * 64 * 4);

  const float ic1 = 1.f / (S1 * KNB);
  const float ic2 = 1.f / (S2 * KNB);

  // ---- stage 1 ----
  fps_kernel<N0, S1, true><<<B_, 512, 0, stream>>>(pc, out3, pc1, out0);
  mid_kernel<<<B_ + S1 * B_, 512, 0, stream>>>(pc, pc1, out4, pc2, out1, nidx1);
  s1a_kernel<<<dim3(2560, B_), dim3(32, 8), 0, stream>>>(pc, feat, nidx1, pc1, pc2, nidx2,
                                                         w1a, b1a, bufA, psum0, psq0);
  linear_norm_kernel<32, 32, 8, 32><<<dim3(512, B_), dim3(32, 8), 0, stream>>>(
      bufA, psum0, psq0, ic1, w1b, b1b, bufB, psum1, psq1, S1 * KNB);
  linear_norm_kernel<32, 32, 8, 32><<<dim3(512, B_), dim3(32, 8), 0, stream>>>(
      bufB, psum1, psq1, ic1, w1c, b1c, bufA, psum0, psq0, S1 * KNB);
  pool1_kernel<<<dim3(512, B_), 256, 0, stream>>>(bufA, psum0, psq0, ic1, f1);

  // ---- stage 2 ----
  lin2a_kernel<<<dim3(512, B_), dim3(64, 4), 0, stream>>>(pc1, f1, nidx2, pc2,
                                                          w2a, b2a, bufB, psum1, psq1);
  linear_norm_kernel<64, 64, 4, 32><<<dim3(512, B_), dim3(64, 4), 0, stream>>>(
      bufB, psum1, psq1, ic2, w2b, b2b, bufA, psum0, psq0, S2 * KNB);
  linear_norm_kernel<64, 64, 4, 32><<<dim3(512, B_), dim3(64, 4), 0, stream>>>(
      bufA, psum0, psq0, ic2, w2c, b2c, bufB, psum1, psq1, S2 * KNB);
  pool2_kernel<<<dim3(512, B_), 256, 0, stream>>>(bufB, psum1, psq1, ic2, out2);
}